// Round 3
// baseline (242.443 us; speedup 1.0000x reference)
//
#include <hip/hip_runtime.h>
#include <math.h>

#define B_SZ 2048
#define R_SZ 64
#define TS 64              // (q,s) tile edge
#define NTILE 32           // 2048 / 64

// B^-0.2 for B=2048: 2^(-2.2)
#define B_POW_NEG02 0.217637640824031f
#define SQRT_2PI 2.5066282746310002f
#define LOG2E 1.44269504088896340736f

// native v_exp_f32 (exp2)
extern "C" __device__ float __ocml_native_exp2_f32(float);

// ---------------------------------------------------------------------------
// ws layout (floats):
//   [0:64)     kscale   = sqrt(0.5*log2e)/h
//   [64:128)   lscale   = 1/(B*h*sqrt(2pi))
//   [128:192)  cov_partial   \ contiguous 128-float block
//   [192:256)  ent_partial   /  reduced by final_kernel
//   [256:...)  density[2048][64]  (512 KB, atomically accumulated)
// ---------------------------------------------------------------------------

// Kernel 1: fused stats + Gram row + covariance row (unchanged from R2).
__global__ __launch_bounds__(1024) void cov_stats_kernel(const float* __restrict__ A,
                                                         float* __restrict__ kscale,
                                                         float* __restrict__ lscale,
                                                         float* __restrict__ cov_partial) {
    int i = blockIdx.x;
    int tid = threadIdx.x;
    int j = tid & 63, bg = tid >> 6;          // 16 b-groups

    float g = 0.f, sj = 0.f;
#pragma unroll 4
    for (int b = bg; b < B_SZ; b += 16) {
        float ai = A[b * R_SZ + i];
        float aj = A[b * R_SZ + j];
        g = fmaf(ai, aj, g);
        sj += aj;
    }

    __shared__ float gred[16][64];
    __shared__ float sred[16][64];
    __shared__ float gfin[64], sfin[64];
    gred[bg][j] = g;
    sred[bg][j] = sj;
    __syncthreads();
    if (tid < 64) {
        float G = 0.f, S = 0.f;
#pragma unroll
        for (int t = 0; t < 16; ++t) { G += gred[t][j]; S += sred[t][j]; }
        gfin[j] = G;
        sfin[j] = S;
    }
    __syncthreads();
    if (tid < 64) {
        float m_j = sfin[j] * (1.f / (float)B_SZ);
        float m_i = sfin[i] * (1.f / (float)B_SZ);
        float cov = (gfin[j] - (float)B_SZ * m_i * m_j) * (1.f / (float)(B_SZ - 1));
        float v = (j == i) ? 0.f : cov * cov;
        for (int off = 32; off > 0; off >>= 1) v += __shfl_down(v, off, 64);
        if (j == 0) cov_partial[i] = v;
        if (j == i) {
            float var = (gfin[i] - sfin[i] * m_i) * (1.f / (float)(B_SZ - 1));
            var = fmaxf(var, 0.f);
            float h = fmaxf(1.06f * sqrtf(var) * B_POW_NEG02, 1e-4f);
            kscale[i] = sqrtf(0.5f * LOG2E) / h;
            lscale[i] = 1.0f / ((float)B_SZ * h * SQRT_2PI);
        }
    }
}

// ---------------------------------------------------------------------------
// Kernel 2: symmetric pairwise KDE. Grid = 32 diag + 496 off-diag tile-pairs.
// Block: 1024 threads = 16 waves; lane = receptor r; wave w owns q rows
// {w, w+16, w+32, w+48}. Each exp serves BOTH density[q] (row accum in regs)
// and density[s] (column accum via staggered LDS float atomics).
// ---------------------------------------------------------------------------
__global__ __launch_bounds__(1024) void kde_sym_kernel(const float* __restrict__ A,
                                                       const float* __restrict__ kscale,
                                                       float* __restrict__ density) {
    __shared__ float Ls[TS][R_SZ];       // pre-scaled sample tile (16 KB)
    __shared__ float colbuf[TS][R_SZ];   // column partial sums    (16 KB)

    int tid = threadIdx.x;
    int r = tid & 63, w = tid >> 6;

    // task decode: t<32 -> diagonal tile t; else upper-triangle pair (ti<tj)
    int t = blockIdx.x;
    int ti, tj;
    bool diag;
    if (t < NTILE) {
        ti = tj = t; diag = true;
    } else {
        int p = t - NTILE; diag = false;
        ti = 0;
        int cnt = NTILE - 1;
        while (p >= cnt) { p -= cnt; ti++; cnt--; }
        tj = ti + 1 + p;
    }
    int q0 = ti * TS, s0 = tj * TS;

    float k = kscale[r];

    // stage pre-scaled S tile + zero column buffer
#pragma unroll
    for (int i = 0; i < 4; ++i) {
        int srow = w + 16 * i;
        Ls[srow][r] = A[(s0 + srow) * R_SZ + r] * k;
        colbuf[srow][r] = 0.f;
    }
    // q fragments straight from global (coalesced, L2-hot)
    float aq0 = A[(q0 + w +  0) * R_SZ + r] * k;
    float aq1 = A[(q0 + w + 16) * R_SZ + r] * k;
    float aq2 = A[(q0 + w + 32) * R_SZ + r] * k;
    float aq3 = A[(q0 + w + 48) * R_SZ + r] * k;
    __syncthreads();

    float r0 = 0.f, r1 = 0.f, r2 = 0.f, r3 = 0.f;
    // staggered s start (4*w) so the 16 waves never collide on colbuf rows
    int sstart = 4 * w;
#pragma unroll 1
    for (int pass = 0; pass < 2; ++pass) {
        int lo = (pass == 0) ? sstart : 0;
        int hi = (pass == 0) ? TS : sstart;
        for (int s = lo; s < hi; ++s) {
            float as = Ls[s][r];
            float d0 = aq0 - as, d1 = aq1 - as, d2 = aq2 - as, d3 = aq3 - as;
            float e0 = __ocml_native_exp2_f32(-d0 * d0);
            float e1 = __ocml_native_exp2_f32(-d1 * d1);
            float e2 = __ocml_native_exp2_f32(-d2 * d2);
            float e3 = __ocml_native_exp2_f32(-d3 * d3);
            r0 += e0; r1 += e1; r2 += e2; r3 += e3;
            if (!diag)   // block-uniform branch; diag tiles skip col work
                atomicAdd(&colbuf[s][r], (e0 + e1) + (e2 + e3));
        }
    }

    // row sums -> global density (many tiles per q-band -> atomics)
    atomicAdd(&density[(q0 + w +  0) * R_SZ + r], r0);
    atomicAdd(&density[(q0 + w + 16) * R_SZ + r], r1);
    atomicAdd(&density[(q0 + w + 32) * R_SZ + r], r2);
    atomicAdd(&density[(q0 + w + 48) * R_SZ + r], r3);

    if (!diag) {
        __syncthreads();
#pragma unroll
        for (int i = 0; i < 4; ++i) {
            int srow = w + 16 * i;
            atomicAdd(&density[(s0 + srow) * R_SZ + r], colbuf[srow][r]);
        }
    }
}

// ---------------------------------------------------------------------------
// Kernel 3: entropy from assembled density. grid 64 x 1024; 2 elems/thread.
// ---------------------------------------------------------------------------
__global__ __launch_bounds__(1024) void entropy_kernel(const float* __restrict__ density,
                                                       const float* __restrict__ lscale,
                                                       float* __restrict__ ent_partial) {
    int tid = threadIdx.x;
    int r = tid & 63;
    float ls = lscale[r];
    int base = blockIdx.x * 2048 + tid;
    float v = __logf(fmaf(density[base], ls, 1e-8f))
            + __logf(fmaf(density[base + 1024], ls, 1e-8f));
    for (int off = 32; off > 0; off >>= 1) v += __shfl_down(v, off, 64);
    __shared__ float wr[16];
    if ((tid & 63) == 0) wr[tid >> 6] = v;
    __syncthreads();
    if (tid == 0) {
        float s = 0.f;
#pragma unroll
        for (int i = 0; i < 16; ++i) s += wr[i];
        ent_partial[blockIdx.x] = s * (1.0f / ((float)B_SZ * (float)R_SZ));
    }
}

// ---------------------------------------------------------------------------
// Kernel 4: final reduce of cov_partial[64] + ent_partial[64] -> out[0]
// ---------------------------------------------------------------------------
__global__ __launch_bounds__(128) void final_kernel(const float* __restrict__ partials,
                                                    float* __restrict__ out) {
    int tid = threadIdx.x;
    float v = partials[tid];
    for (int off = 32; off > 0; off >>= 1) v += __shfl_down(v, off, 64);
    __shared__ float wr[2];
    if ((tid & 63) == 0) wr[tid >> 6] = v;
    __syncthreads();
    if (tid == 0) out[0] = wr[0] + wr[1];
}

extern "C" void kernel_launch(void* const* d_in, const int* in_sizes, int n_in,
                              void* d_out, int out_size, void* d_ws, size_t ws_size,
                              hipStream_t stream) {
    const float* A = (const float*)d_in[0];
    float* out = (float*)d_out;

    float* wsf = (float*)d_ws;
    float* kscale      = wsf;            // 64
    float* lscale      = wsf + 64;       // 64
    float* cov_partial = wsf + 128;      // 64  \ contiguous 128 floats
    float* ent_partial = wsf + 192;      // 64  /
    float* density     = wsf + 256;      // 2048*64

    hipMemsetAsync((void*)density, 0, B_SZ * R_SZ * sizeof(float), stream);
    cov_stats_kernel<<<R_SZ, 1024, 0, stream>>>(A, kscale, lscale, cov_partial);
    kde_sym_kernel<<<NTILE + (NTILE * (NTILE - 1)) / 2, 1024, 0, stream>>>(A, kscale, density);
    entropy_kernel<<<64, 1024, 0, stream>>>(density, lscale, ent_partial);
    final_kernel<<<1, 128, 0, stream>>>(cov_partial, out);
}

// Round 4
// 108.634 us; speedup vs baseline: 2.2317x; 2.2317x over previous
//
#include <hip/hip_runtime.h>
#include <math.h>

#define B_SZ 2048
#define R_SZ 64
#define QT 4                    // q rows per kde block
#define CH 128                  // s rows staged per LDS chunk
#define NCHUNK (B_SZ / CH)      // 16
#define KDE_BLOCKS (B_SZ / QT)  // 512 blocks * 16 waves = 8192 waves = 100% occ

#define B_POW_NEG02 0.217637640824031f   // 2048^-0.2 = 2^-2.2
#define SQRT_2PI 2.5066282746310002f
#define LOG2E 1.44269504088896340736f

// native v_exp_f32 (exp2)
extern "C" __device__ float __ocml_native_exp2_f32(float);

// ---------------------------------------------------------------------------
// ws layout (floats):
//   [0:64)    lscale       = 1/(B*h*sqrt(2pi))
//   [64:128)  cov_partial  (one per receptor row)
//   [160]     ent_acc      (own 128B line: only ever touched by L2 atomics)
//   [192]     done_cnt     (int, own line)
//   [256:256+131072)  U = kscale[r]*A  (prescaled input, 512 KB)
// ---------------------------------------------------------------------------

// Kernel 1: fused stats + Gram row + cov row + U prescale + flag init.
// grid 64 blocks x 1024. Block i: Gram row i; every block also computes the
// FULL h vector (needs only per-j sum/sumsq) so it can prescale its U slice.
__global__ __launch_bounds__(1024) void cov_stats_kernel(const float* __restrict__ A,
                                                         float* __restrict__ U,
                                                         float* __restrict__ lscale,
                                                         float* __restrict__ cov_partial,
                                                         float* __restrict__ ent_acc,
                                                         int* __restrict__ done_cnt) {
    int i = blockIdx.x;
    int tid = threadIdx.x;
    int j = tid & 63, bg = tid >> 6;          // 16 b-groups

    float g = 0.f, sj = 0.f, s2j = 0.f;
#pragma unroll 4
    for (int b = bg; b < B_SZ; b += 16) {
        float ai = A[b * R_SZ + i];           // wave-uniform broadcast (L1 hit)
        float aj = A[b * R_SZ + j];           // coalesced
        g = fmaf(ai, aj, g);
        sj += aj;
        s2j = fmaf(aj, aj, s2j);
    }

    __shared__ float gred[16][64], sred[16][64], s2red[16][64];
    __shared__ float gfin[64], sfin[64], hs[64];
    gred[bg][j] = g; sred[bg][j] = sj; s2red[bg][j] = s2j;
    __syncthreads();
    if (tid < 64) {
        float G = 0.f, S = 0.f, S2 = 0.f;
#pragma unroll
        for (int t = 0; t < 16; ++t) { G += gred[t][j]; S += sred[t][j]; S2 += s2red[t][j]; }
        gfin[j] = G;
        sfin[j] = S;
        float m = S * (1.f / (float)B_SZ);
        float var = (S2 - S * m) * (1.f / (float)(B_SZ - 1));   // ddof=1
        var = fmaxf(var, 0.f);
        float h = fmaxf(1.06f * sqrtf(var) * B_POW_NEG02, 1e-4f);
        hs[j] = sqrtf(0.5f * LOG2E) / h;      // kscale: exp2(-(k*d)^2) = exp(-0.5(d/h)^2)
        if (i == 0) lscale[j] = 1.0f / ((float)B_SZ * h * SQRT_2PI);
    }
    __syncthreads();
    if (tid < 64) {                            // covariance row i
        float m_j = sfin[j] * (1.f / (float)B_SZ);
        float m_i = sfin[i] * (1.f / (float)B_SZ);
        float cov = (gfin[j] - (float)B_SZ * m_i * m_j) * (1.f / (float)(B_SZ - 1));
        float v = (j == i) ? 0.f : cov * cov;
        for (int off = 32; off > 0; off >>= 1) v += __shfl_down(v, off, 64);
        if (j == 0) cov_partial[i] = v;
    }
    if (i == 0 && tid == 64) { *ent_acc = 0.f; *done_cnt = 0; }

    // prescale U rows [i*32, i*32+32): 2048 elems, 2 per thread (coalesced)
    int base = i * (32 * R_SZ);
    float k0 = hs[tid & 63];
    U[base + tid]        = A[base + tid]        * k0;
    U[base + 1024 + tid] = A[base + 1024 + tid] * k0;
}

// ---------------------------------------------------------------------------
// Kernel 2: pairwise KDE + entropy + grid-final fold.
// 512 blocks x 1024 thr. Block owns QT=4 query rows (registers, prescaled);
// s dimension staged through LDS in 128-row chunks; wave sg covers
// s = sg + 16*it within each chunk. Inner iter: 1 ds_read + 4x(sub,negmul,
// exp2, add). No atomics in the loop. Last block folds cov+ent -> out[0].
// ---------------------------------------------------------------------------
__global__ __launch_bounds__(1024) void kde_kernel(const float* __restrict__ U,
                                                   const float* __restrict__ lscale,
                                                   const float* __restrict__ cov_partial,
                                                   float* __restrict__ ent_acc,
                                                   int* __restrict__ done_cnt,
                                                   float* __restrict__ out) {
    __shared__ float Us[CH * R_SZ];            // 32 KB; reused for reductions
    int tid = threadIdx.x;
    int r = tid & 63, sg = tid >> 6;
    int q0 = blockIdx.x * QT;

    float uq0 = U[(q0 + 0) * R_SZ + r];
    float uq1 = U[(q0 + 1) * R_SZ + r];
    float uq2 = U[(q0 + 2) * R_SZ + r];
    float uq3 = U[(q0 + 3) * R_SZ + r];
    float c0 = 0.f, c1 = 0.f, c2 = 0.f, c3 = 0.f;

    for (int ch = 0; ch < NCHUNK; ++ch) {
        const float4* src = (const float4*)(U + ch * (CH * R_SZ));
        float4* dst = (float4*)Us;
        dst[tid]        = src[tid];            // 16 KB
        dst[tid + 1024] = src[tid + 1024];     // 16 KB
        __syncthreads();
#pragma unroll
        for (int it = 0; it < CH / 16; ++it) { // 8 iters, imm-offset ds_reads
            float us = Us[(sg + 16 * it) * R_SZ + r];
            float d0 = uq0 - us; c0 += __ocml_native_exp2_f32(-d0 * d0);
            float d1 = uq1 - us; c1 += __ocml_native_exp2_f32(-d1 * d1);
            float d2 = uq2 - us; c2 += __ocml_native_exp2_f32(-d2 * d2);
            float d3 = uq3 - us; c3 += __ocml_native_exp2_f32(-d3 * d3);
        }
        __syncthreads();
    }

    // cross-wave reduction of the 4 query-row densities (reuse Us as [16][4][64])
    float (*red)[QT][64] = (float (*)[QT][64])Us;
    red[sg][0][r] = c0;
    red[sg][1][r] = c1;
    red[sg][2][r] = c2;
    red[sg][3][r] = c3;
    __syncthreads();
    __shared__ float wred[QT];
    if (sg < QT) {                             // wave sg owns query row sg
        float S = 0.f;
#pragma unroll
        for (int t = 0; t < 16; ++t) S += red[t][sg][r];
        float v = __logf(fmaf(S, lscale[r], 1e-8f));
        for (int off = 32; off > 0; off >>= 1) v += __shfl_down(v, off, 64);
        if (r == 0) wred[sg] = v;
    }
    __syncthreads();
    __shared__ int lastflag;
    if (tid == 0) {
        float p = (wred[0] + wred[1] + wred[2] + wred[3]) *
                  (1.0f / ((float)B_SZ * (float)R_SZ));
        atomicAdd(ent_acc, p);                 // once per block: CAS loop is fine
        __threadfence();
        int prev = atomicAdd(done_cnt, 1);
        lastflag = (prev == KDE_BLOCKS - 1);
    }
    __syncthreads();
    if (lastflag && tid < 64) {                // grid-final fold in last block
        __threadfence();
        float v = cov_partial[tid];
        for (int off = 32; off > 0; off >>= 1) v += __shfl_down(v, off, 64);
        if (tid == 0) {
            float ent = __hip_atomic_load(ent_acc, __ATOMIC_ACQUIRE,
                                          __HIP_MEMORY_SCOPE_AGENT);
            out[0] = ent + v;                  // COV_WEIGHT = 1.0
        }
    }
}

extern "C" void kernel_launch(void* const* d_in, const int* in_sizes, int n_in,
                              void* d_out, int out_size, void* d_ws, size_t ws_size,
                              hipStream_t stream) {
    const float* A = (const float*)d_in[0];
    float* out = (float*)d_out;

    float* wsf = (float*)d_ws;
    float* lscale      = wsf;            // 64
    float* cov_partial = wsf + 64;       // 64
    float* ent_acc     = wsf + 160;      // isolated cache line
    int*   done_cnt    = (int*)(wsf + 192);
    float* U           = wsf + 256;      // 2048*64 prescaled input

    cov_stats_kernel<<<R_SZ, 1024, 0, stream>>>(A, U, lscale, cov_partial,
                                                ent_acc, done_cnt);
    kde_kernel<<<KDE_BLOCKS, 1024, 0, stream>>>(U, lscale, cov_partial,
                                                ent_acc, done_cnt, out);
}

// Round 5
// 107.027 us; speedup vs baseline: 2.2653x; 1.0150x over previous
//
#include <hip/hip_runtime.h>
#include <math.h>

#define B_SZ 2048
#define R_SZ 64
#define QT 4                    // q rows per kde block
#define KDE_BLOCKS (B_SZ / QT)  // 512 blocks * 16 waves = 8192 waves = 100% occ

#define B_POW_NEG02 0.217637640824031f   // 2048^-0.2 = 2^-2.2
#define SQRT_2PI 2.5066282746310002f
#define LOG2E 1.44269504088896340736f

// native v_exp_f32 (exp2)
extern "C" __device__ float __ocml_native_exp2_f32(float);

typedef __attribute__((ext_vector_type(2))) float f32x2;  // -> v_pk_* f32 ops

// ---------------------------------------------------------------------------
// ws layout (floats):
//   [0:64)    lscale       = 1/(B*h*sqrt(2pi))
//   [64:128)  cov_partial  (one per receptor row)
//   [160]     ent_acc      (own 128B line)
//   [192]     done_cnt     (int, own line)
//   [256:256+131072)  U = kscale[r]*A  (prescaled input, 512 KB)
// ---------------------------------------------------------------------------

// Kernel 1: fused stats + Gram row + cov row + U prescale + flag init.
// (unchanged from R4 — verified correct)
__global__ __launch_bounds__(1024) void cov_stats_kernel(const float* __restrict__ A,
                                                         float* __restrict__ U,
                                                         float* __restrict__ lscale,
                                                         float* __restrict__ cov_partial,
                                                         float* __restrict__ ent_acc,
                                                         int* __restrict__ done_cnt) {
    int i = blockIdx.x;
    int tid = threadIdx.x;
    int j = tid & 63, bg = tid >> 6;          // 16 b-groups

    float g = 0.f, sj = 0.f, s2j = 0.f;
#pragma unroll 4
    for (int b = bg; b < B_SZ; b += 16) {
        float ai = A[b * R_SZ + i];           // wave-uniform broadcast
        float aj = A[b * R_SZ + j];           // coalesced
        g = fmaf(ai, aj, g);
        sj += aj;
        s2j = fmaf(aj, aj, s2j);
    }

    __shared__ float gred[16][64], sred[16][64], s2red[16][64];
    __shared__ float gfin[64], sfin[64], hs[64];
    gred[bg][j] = g; sred[bg][j] = sj; s2red[bg][j] = s2j;
    __syncthreads();
    if (tid < 64) {
        float G = 0.f, S = 0.f, S2 = 0.f;
#pragma unroll
        for (int t = 0; t < 16; ++t) { G += gred[t][j]; S += sred[t][j]; S2 += s2red[t][j]; }
        gfin[j] = G;
        sfin[j] = S;
        float m = S * (1.f / (float)B_SZ);
        float var = (S2 - S * m) * (1.f / (float)(B_SZ - 1));   // ddof=1
        var = fmaxf(var, 0.f);
        float h = fmaxf(1.06f * sqrtf(var) * B_POW_NEG02, 1e-4f);
        hs[j] = sqrtf(0.5f * LOG2E) / h;      // exp2(-(k*d)^2) = exp(-0.5(d/h)^2)
        if (i == 0) lscale[j] = 1.0f / ((float)B_SZ * h * SQRT_2PI);
    }
    __syncthreads();
    if (tid < 64) {                            // covariance row i
        float m_j = sfin[j] * (1.f / (float)B_SZ);
        float m_i = sfin[i] * (1.f / (float)B_SZ);
        float cov = (gfin[j] - (float)B_SZ * m_i * m_j) * (1.f / (float)(B_SZ - 1));
        float v = (j == i) ? 0.f : cov * cov;
        for (int off = 32; off > 0; off >>= 1) v += __shfl_down(v, off, 64);
        if (j == 0) cov_partial[i] = v;
    }
    if (i == 0 && tid == 64) { *ent_acc = 0.f; *done_cnt = 0; }

    // prescale U rows [i*32, i*32+32): 2048 elems, 2 per thread (coalesced)
    int base = i * (32 * R_SZ);
    float k0 = hs[tid & 63];
    U[base + tid]        = A[base + tid]        * k0;
    U[base + 1024 + tid] = A[base + 1024 + tid] * k0;
}

// ---------------------------------------------------------------------------
// Kernel 2: pairwise KDE, barrier-free streaming + packed-f32 math.
// 512 blocks x 1024 thr. Block owns QT=4 query rows held as two f32x2 pairs;
// wave sg streams s = sg, sg+16, ... from global (L1/L2-hot, coalesced).
// Per iter: 1 load + pk_sub/pk_negmul/pk_acc per pair + 4 v_exp_f32.
// No barriers, no atomics in the loop. Last block folds cov+ent -> out[0].
// ---------------------------------------------------------------------------
__global__ __launch_bounds__(1024) void kde_kernel(const float* __restrict__ U,
                                                   const float* __restrict__ lscale,
                                                   const float* __restrict__ cov_partial,
                                                   float* __restrict__ ent_acc,
                                                   int* __restrict__ done_cnt,
                                                   float* __restrict__ out) {
    int tid = threadIdx.x;
    int r = tid & 63, sg = tid >> 6;
    int q0 = blockIdx.x * QT;

    f32x2 uq01 = { U[(q0 + 0) * R_SZ + r], U[(q0 + 1) * R_SZ + r] };
    f32x2 uq23 = { U[(q0 + 2) * R_SZ + r], U[(q0 + 3) * R_SZ + r] };
    f32x2 c01 = { 0.f, 0.f }, c23 = { 0.f, 0.f };

#pragma unroll 4
    for (int s = sg; s < B_SZ; s += 16) {
        float us = U[s * R_SZ + r];
        f32x2 uss = { us, us };
        f32x2 d01 = uq01 - uss;                // v_pk_add (neg)
        f32x2 d23 = uq23 - uss;
        f32x2 n01 = -d01 * d01;                // v_pk_mul (neg)
        f32x2 n23 = -d23 * d23;
        f32x2 e01 = { __ocml_native_exp2_f32(n01.x), __ocml_native_exp2_f32(n01.y) };
        f32x2 e23 = { __ocml_native_exp2_f32(n23.x), __ocml_native_exp2_f32(n23.y) };
        c01 += e01;                            // v_pk_add
        c23 += e23;
    }

    // cross-wave reduction of the 4 query-row densities
    __shared__ float red[16][QT][64];
    red[sg][0][r] = c01.x;
    red[sg][1][r] = c01.y;
    red[sg][2][r] = c23.x;
    red[sg][3][r] = c23.y;
    __syncthreads();
    __shared__ float wred[QT];
    if (sg < QT) {                             // wave sg owns query row sg
        float S = 0.f;
#pragma unroll
        for (int t = 0; t < 16; ++t) S += red[t][sg][r];
        float v = __logf(fmaf(S, lscale[r], 1e-8f));
        for (int off = 32; off > 0; off >>= 1) v += __shfl_down(v, off, 64);
        if (r == 0) wred[sg] = v;
    }
    __syncthreads();
    __shared__ int lastflag;
    if (tid == 0) {
        float p = (wred[0] + wred[1] + wred[2] + wred[3]) *
                  (1.0f / ((float)B_SZ * (float)R_SZ));
        atomicAdd(ent_acc, p);                 // once per block
        __threadfence();
        int prev = atomicAdd(done_cnt, 1);
        lastflag = (prev == KDE_BLOCKS - 1);
    }
    __syncthreads();
    if (lastflag && tid < 64) {                // grid-final fold in last block
        __threadfence();
        float v = cov_partial[tid];
        for (int off = 32; off > 0; off >>= 1) v += __shfl_down(v, off, 64);
        if (tid == 0) {
            float ent = __hip_atomic_load(ent_acc, __ATOMIC_ACQUIRE,
                                          __HIP_MEMORY_SCOPE_AGENT);
            out[0] = ent + v;                  // COV_WEIGHT = 1.0
        }
    }
}

extern "C" void kernel_launch(void* const* d_in, const int* in_sizes, int n_in,
                              void* d_out, int out_size, void* d_ws, size_t ws_size,
                              hipStream_t stream) {
    const float* A = (const float*)d_in[0];
    float* out = (float*)d_out;

    float* wsf = (float*)d_ws;
    float* lscale      = wsf;            // 64
    float* cov_partial = wsf + 64;       // 64
    float* ent_acc     = wsf + 160;      // isolated cache line
    int*   done_cnt    = (int*)(wsf + 192);
    float* U           = wsf + 256;      // 2048*64 prescaled input

    cov_stats_kernel<<<R_SZ, 1024, 0, stream>>>(A, U, lscale, cov_partial,
                                                ent_acc, done_cnt);
    kde_kernel<<<KDE_BLOCKS, 1024, 0, stream>>>(U, lscale, cov_partial,
                                                ent_acc, done_cnt, out);
}

// Round 6
// 103.329 us; speedup vs baseline: 2.3463x; 1.0358x over previous
//
#include <hip/hip_runtime.h>
#include <math.h>

#define B_SZ 2048
#define R_SZ 64
#define QT 8                    // q rows per kde block
#define KDE_BLOCKS (B_SZ / QT)  // 256 blocks * 16 waves -> 1 block/CU

#define B_POW_NEG02 0.217637640824031f   // 2048^-0.2 = 2^-2.2
#define SQRT_2PI 2.5066282746310002f
#define LOG2E 1.44269504088896340736f

// native v_exp_f32 (exp2)
extern "C" __device__ float __ocml_native_exp2_f32(float);

typedef __attribute__((ext_vector_type(2))) float f32x2;  // -> v_pk_* f32 ops

// ---------------------------------------------------------------------------
// ws layout (floats):
//   [0:64)    lscale       = 1/(B*h*sqrt(2pi))
//   [64:128)  cov_partial  (one per receptor row)
//   [160]     ent_acc      (own 128B line)
//   [192]     done_cnt     (int, own line)
//   [256:256+131072)  U = kscale[r]*A  (prescaled input, 512 KB)
// ---------------------------------------------------------------------------

// Kernel 1: fused stats + Gram row + cov row + U prescale + flag init.
// (unchanged — verified correct since R4)
__global__ __launch_bounds__(1024) void cov_stats_kernel(const float* __restrict__ A,
                                                         float* __restrict__ U,
                                                         float* __restrict__ lscale,
                                                         float* __restrict__ cov_partial,
                                                         float* __restrict__ ent_acc,
                                                         int* __restrict__ done_cnt) {
    int i = blockIdx.x;
    int tid = threadIdx.x;
    int j = tid & 63, bg = tid >> 6;          // 16 b-groups

    float g = 0.f, sj = 0.f, s2j = 0.f;
#pragma unroll 4
    for (int b = bg; b < B_SZ; b += 16) {
        float ai = A[b * R_SZ + i];           // wave-uniform broadcast
        float aj = A[b * R_SZ + j];           // coalesced
        g = fmaf(ai, aj, g);
        sj += aj;
        s2j = fmaf(aj, aj, s2j);
    }

    __shared__ float gred[16][64], sred[16][64], s2red[16][64];
    __shared__ float gfin[64], sfin[64], hs[64];
    gred[bg][j] = g; sred[bg][j] = sj; s2red[bg][j] = s2j;
    __syncthreads();
    if (tid < 64) {
        float G = 0.f, S = 0.f, S2 = 0.f;
#pragma unroll
        for (int t = 0; t < 16; ++t) { G += gred[t][j]; S += sred[t][j]; S2 += s2red[t][j]; }
        gfin[j] = G;
        sfin[j] = S;
        float m = S * (1.f / (float)B_SZ);
        float var = (S2 - S * m) * (1.f / (float)(B_SZ - 1));   // ddof=1
        var = fmaxf(var, 0.f);
        float h = fmaxf(1.06f * sqrtf(var) * B_POW_NEG02, 1e-4f);
        hs[j] = sqrtf(0.5f * LOG2E) / h;      // exp2(-(k*d)^2) = exp(-0.5(d/h)^2)
        if (i == 0) lscale[j] = 1.0f / ((float)B_SZ * h * SQRT_2PI);
    }
    __syncthreads();
    if (tid < 64) {                            // covariance row i
        float m_j = sfin[j] * (1.f / (float)B_SZ);
        float m_i = sfin[i] * (1.f / (float)B_SZ);
        float cov = (gfin[j] - (float)B_SZ * m_i * m_j) * (1.f / (float)(B_SZ - 1));
        float v = (j == i) ? 0.f : cov * cov;
        for (int off = 32; off > 0; off >>= 1) v += __shfl_down(v, off, 64);
        if (j == 0) cov_partial[i] = v;
    }
    if (i == 0 && tid == 64) { *ent_acc = 0.f; *done_cnt = 0; }

    // prescale U rows [i*32, i*32+32): 2048 elems, 2 per thread (coalesced)
    int base = i * (32 * R_SZ);
    float k0 = hs[tid & 63];
    U[base + tid]        = A[base + tid]        * k0;
    U[base + 1024 + tid] = A[base + 1024 + tid] * k0;
}

// ---------------------------------------------------------------------------
// Kernel 2: pairwise KDE, barrier-free streaming, QT=8 queries/block.
// 256 blocks x 1024 thr (1 block/CU). Block owns 8 query rows as 4 f32x2
// pairs; wave sg streams s = sg, sg+16, ... Per iter: 1 load + 12 pk-VALU +
// 8 v_exp_f32 -> 8 exps amortize one L1-mostly-hit load. No barriers or
// atomics in the loop. Last block folds cov+ent -> out[0].
// ---------------------------------------------------------------------------
__global__ __launch_bounds__(1024) void kde_kernel(const float* __restrict__ U,
                                                   const float* __restrict__ lscale,
                                                   const float* __restrict__ cov_partial,
                                                   float* __restrict__ ent_acc,
                                                   int* __restrict__ done_cnt,
                                                   float* __restrict__ out) {
    int tid = threadIdx.x;
    int r = tid & 63, sg = tid >> 6;
    int q0 = blockIdx.x * QT;

    f32x2 uq01 = { U[(q0 + 0) * R_SZ + r], U[(q0 + 1) * R_SZ + r] };
    f32x2 uq23 = { U[(q0 + 2) * R_SZ + r], U[(q0 + 3) * R_SZ + r] };
    f32x2 uq45 = { U[(q0 + 4) * R_SZ + r], U[(q0 + 5) * R_SZ + r] };
    f32x2 uq67 = { U[(q0 + 6) * R_SZ + r], U[(q0 + 7) * R_SZ + r] };
    f32x2 c01 = { 0.f, 0.f }, c23 = { 0.f, 0.f };
    f32x2 c45 = { 0.f, 0.f }, c67 = { 0.f, 0.f };

#pragma unroll 4
    for (int s = sg; s < B_SZ; s += 16) {
        float us = U[s * R_SZ + r];
        f32x2 uss = { us, us };
        f32x2 d01 = uq01 - uss, d23 = uq23 - uss;
        f32x2 d45 = uq45 - uss, d67 = uq67 - uss;
        f32x2 n01 = -d01 * d01, n23 = -d23 * d23;
        f32x2 n45 = -d45 * d45, n67 = -d67 * d67;
        f32x2 e01 = { __ocml_native_exp2_f32(n01.x), __ocml_native_exp2_f32(n01.y) };
        f32x2 e23 = { __ocml_native_exp2_f32(n23.x), __ocml_native_exp2_f32(n23.y) };
        f32x2 e45 = { __ocml_native_exp2_f32(n45.x), __ocml_native_exp2_f32(n45.y) };
        f32x2 e67 = { __ocml_native_exp2_f32(n67.x), __ocml_native_exp2_f32(n67.y) };
        c01 += e01; c23 += e23; c45 += e45; c67 += e67;
    }

    // cross-wave reduction of the 8 query-row densities (32 KB LDS)
    __shared__ float red[16][QT][64];
    red[sg][0][r] = c01.x; red[sg][1][r] = c01.y;
    red[sg][2][r] = c23.x; red[sg][3][r] = c23.y;
    red[sg][4][r] = c45.x; red[sg][5][r] = c45.y;
    red[sg][6][r] = c67.x; red[sg][7][r] = c67.y;
    __syncthreads();
    __shared__ float wred[QT];
    if (sg < QT) {                             // wave sg owns query row sg
        float S = 0.f;
#pragma unroll
        for (int t = 0; t < 16; ++t) S += red[t][sg][r];
        float v = __logf(fmaf(S, lscale[r], 1e-8f));
        for (int off = 32; off > 0; off >>= 1) v += __shfl_down(v, off, 64);
        if (r == 0) wred[sg] = v;
    }
    __syncthreads();
    __shared__ int lastflag;
    if (tid == 0) {
        float p = 0.f;
#pragma unroll
        for (int t = 0; t < QT; ++t) p += wred[t];
        p *= (1.0f / ((float)B_SZ * (float)R_SZ));
        atomicAdd(ent_acc, p);                 // once per block
        __threadfence();
        int prev = atomicAdd(done_cnt, 1);
        lastflag = (prev == KDE_BLOCKS - 1);
    }
    __syncthreads();
    if (lastflag && tid < 64) {                // grid-final fold in last block
        __threadfence();
        float v = cov_partial[tid];
        for (int off = 32; off > 0; off >>= 1) v += __shfl_down(v, off, 64);
        if (tid == 0) {
            float ent = __hip_atomic_load(ent_acc, __ATOMIC_ACQUIRE,
                                          __HIP_MEMORY_SCOPE_AGENT);
            out[0] = ent + v;                  // COV_WEIGHT = 1.0
        }
    }
}

extern "C" void kernel_launch(void* const* d_in, const int* in_sizes, int n_in,
                              void* d_out, int out_size, void* d_ws, size_t ws_size,
                              hipStream_t stream) {
    const float* A = (const float*)d_in[0];
    float* out = (float*)d_out;

    float* wsf = (float*)d_ws;
    float* lscale      = wsf;            // 64
    float* cov_partial = wsf + 64;       // 64
    float* ent_acc     = wsf + 160;      // isolated cache line
    int*   done_cnt    = (int*)(wsf + 192);
    float* U           = wsf + 256;      // 2048*64 prescaled input

    cov_stats_kernel<<<R_SZ, 1024, 0, stream>>>(A, U, lscale, cov_partial,
                                                ent_acc, done_cnt);
    kde_kernel<<<KDE_BLOCKS, 1024, 0, stream>>>(U, lscale, cov_partial,
                                                ent_acc, done_cnt, out);
}